// Round 1
// baseline (30.978 us; speedup 1.0000x reference)
//
#include <hip/hip_runtime.h>

#define LDIM 16
#define CDIM 3
#define HW (512 * 512)
#define NCH (LDIM * CDIM)   // 48 channels
#define BPC 40              // blocks per channel
#define TPB 256
#define V_EPS 1e-5

// Kernel 1: per-block partial sums of {e*e*m, c*e*m, c*c*m, m} over one channel.
__global__ __launch_bounds__(TPB) void smse_partials(
    const float* __restrict__ correct,
    const float* __restrict__ estimate,
    const float* __restrict__ mask,
    float* __restrict__ partials)  // [NCH * BPC * 4]
{
    const int ch  = blockIdx.x / BPC;
    const int bin = blockIdx.x % BPC;

    const float4* __restrict__ c4 = (const float4*)(correct  + (size_t)ch * HW);
    const float4* __restrict__ e4 = (const float4*)(estimate + (size_t)ch * HW);
    const float4* __restrict__ m4 = (const float4*)(mask     + (size_t)ch * HW);
    const int N4 = HW / 4;  // 65536 float4 per channel

    float se2m = 0.f, scem = 0.f, sc2m = 0.f, sm = 0.f;
    for (int i = bin * TPB + threadIdx.x; i < N4; i += BPC * TPB) {
        float4 c = c4[i];
        float4 e = e4[i];
        float4 m = m4[i];
        se2m += e.x*e.x*m.x + e.y*e.y*m.y + e.z*e.z*m.z + e.w*e.w*m.w;
        scem += c.x*e.x*m.x + c.y*e.y*m.y + c.z*e.z*m.z + c.w*e.w*m.w;
        sc2m += c.x*c.x*m.x + c.y*c.y*m.y + c.z*c.z*m.z + c.w*c.w*m.w;
        sm   += m.x + m.y + m.z + m.w;
    }

    // Wave64 butterfly reduce of the 4 accumulators.
    #pragma unroll
    for (int off = 32; off > 0; off >>= 1) {
        se2m += __shfl_down(se2m, off);
        scem += __shfl_down(scem, off);
        sc2m += __shfl_down(sc2m, off);
        sm   += __shfl_down(sm,   off);
    }

    __shared__ float4 red[TPB / 64];  // one float4 per wave
    const int wave = threadIdx.x >> 6;
    const int lane = threadIdx.x & 63;
    if (lane == 0) red[wave] = make_float4(se2m, scem, sc2m, sm);
    __syncthreads();

    if (threadIdx.x == 0) {
        float4 s = red[0];
        #pragma unroll
        for (int w = 1; w < TPB / 64; ++w) {
            float4 r = red[w];
            s.x += r.x; s.y += r.y; s.z += r.z; s.w += r.w;
        }
        float* p = partials + ((size_t)ch * BPC + bin) * 4;
        p[0] = s.x; p[1] = s.y; p[2] = s.z; p[3] = s.w;
    }
}

// Kernel 2: reduce BPC partials per channel, apply alpha/err formula, reduce
// over all 48 channels to the scalar loss.
__global__ __launch_bounds__(64) void smse_final(
    const float* __restrict__ partials,
    float* __restrict__ out)
{
    const int t = threadIdx.x;  // 64 threads, one wave
    float val = 0.f;
    if (t < NCH) {
        double v = 0.0, num = 0.0, cc = 0.0, ms = 0.0;
        for (int b = 0; b < BPC; ++b) {
            const float* p = partials + ((size_t)t * BPC + b) * 4;
            v   += p[0];
            num += p[1];
            cc  += p[2];
            ms  += p[3];
        }
        double alpha = (v > V_EPS) ? (num / v) : 0.0;
        double err = cc - alpha * (2.0 * num - alpha * v);
        val = (float)(err / ms);
    }
    #pragma unroll
    for (int off = 32; off > 0; off >>= 1) val += __shfl_down(val, off);
    if (t == 0) out[0] = val / (float)NCH;
}

extern "C" void kernel_launch(void* const* d_in, const int* in_sizes, int n_in,
                              void* d_out, int out_size, void* d_ws, size_t ws_size,
                              hipStream_t stream) {
    const float* correct  = (const float*)d_in[0];
    const float* estimate = (const float*)d_in[1];
    const float* mask     = (const float*)d_in[2];
    float* out = (float*)d_out;
    float* partials = (float*)d_ws;  // NCH*BPC*4 floats = 30 KiB

    smse_partials<<<NCH * BPC, TPB, 0, stream>>>(correct, estimate, mask, partials);
    smse_final<<<1, 64, 0, stream>>>(partials, out);
}